// Round 6
// baseline (99.230 us; speedup 1.0000x reference)
//
#include <hip/hip_runtime.h>
#include <math.h>

#define WAVES_PER_BLOCK 4

typedef float v2f __attribute__((ext_vector_type(2)));
typedef float v4f __attribute__((ext_vector_type(4)));
typedef __fp16 fp16v2 __attribute__((ext_vector_type(2)));
typedef _Float16 half8 __attribute__((ext_vector_type(8)));

__device__ __forceinline__ v2f v2_fma(v2f a, v2f b, v2f c) {
    return __builtin_elementwise_fma(a, b, c);
}
__device__ __forceinline__ v2f v2_max0(v2f a) {
    return __builtin_elementwise_max(a, (v2f){0.0f, 0.0f});
}
__device__ __forceinline__ v2f v2_splat(float x) { return (v2f){x, x}; }

__device__ __forceinline__ float fast_rcp(float x) { return __builtin_amdgcn_rcpf(x); }

// ---------------- DPP cross-lane primitives ----------------
#define DPP_ROW_SHR(n)  (0x110 | (n))
#define DPP_WF_SL1      0x130
#define DPP_WF_SR1      0x138
#define DPP_ROW_BCAST15 0x142
#define DPP_ROW_BCAST31 0x143

template <int CTRL, int RM = 0xf, int BM = 0xf, bool BC = false>
__device__ __forceinline__ float fdpp(float old_, float src) {
    return __int_as_float(__builtin_amdgcn_update_dpp(
        __float_as_int(old_), __float_as_int(src), CTRL, RM, BM, BC));
}

__device__ __forceinline__ float lane63_bcast(float x) {
    return __int_as_float(__builtin_amdgcn_readlane(__float_as_int(x), 63));
}

__device__ __forceinline__ float scan_add_dpp(float x) {
    x += fdpp<DPP_ROW_SHR(1)>(0.0f, x);
    x += fdpp<DPP_ROW_SHR(2)>(0.0f, x);
    x += fdpp<DPP_ROW_SHR(4)>(0.0f, x);
    x += fdpp<DPP_ROW_SHR(8)>(0.0f, x);
    x += fdpp<DPP_ROW_BCAST15, 0xa>(0.0f, x);
    x += fdpp<DPP_ROW_BCAST31, 0xc>(0.0f, x);
    return x;
}
__device__ __forceinline__ float scan_mul_dpp(float x) {
    x *= fdpp<DPP_ROW_SHR(1)>(1.0f, x);
    x *= fdpp<DPP_ROW_SHR(2)>(1.0f, x);
    x *= fdpp<DPP_ROW_SHR(4)>(1.0f, x);
    x *= fdpp<DPP_ROW_SHR(8)>(1.0f, x);
    x *= fdpp<DPP_ROW_BCAST15, 0xa>(1.0f, x);
    x *= fdpp<DPP_ROW_BCAST31, 0xc>(1.0f, x);
    return x;
}
__device__ __forceinline__ float wave_sum_dpp(float x) {
    return lane63_bcast(scan_add_dpp(x));
}

__device__ __forceinline__ float softplus_f(float x) {
    return fmaxf(x, 0.0f) + __logf(1.0f + __expf(-fabsf(x)));
}
__device__ __forceinline__ float sigmoid_f(float x) {
    return fast_rcp(1.0f + __expf(-x));
}
__device__ __forceinline__ float clamp1(float x) {
    return fminf(fmaxf(x, -1.0f), 1.0f);
}

__device__ __forceinline__ int count_lt64(const float* a, float x) {
    int lo = 0, hi = 64;
    while (lo < hi) { int mid = (lo + hi) >> 1; if (a[mid] < x) lo = mid + 1; else hi = mid; }
    return lo;
}
__device__ __forceinline__ int count_le64(const float* a, float x) {
    int lo = 0, hi = 64;
    while (lo < hi) { int mid = (lo + hi) >> 1; if (a[mid] <= x) lo = mid + 1; else hi = mid; }
    return lo;
}

__global__ __launch_bounds__(WAVES_PER_BLOCK * 64, 8)
void nerf_render_kernel(const float* __restrict__ rays_o,
                        const float* __restrict__ rays_d,
                        const float* __restrict__ W1,      // [3,64]
                        const float* __restrict__ b1,      // [64]
                        const float* __restrict__ w_sigma, // [64,1]
                        const float* __restrict__ b_sigma, // [1]
                        const float* __restrict__ W_rgb,   // [64,3]
                        const float* __restrict__ b_rgb,   // [3]
                        float* __restrict__ out)           // [N,3]
{
    const int tid  = threadIdx.x;
    const int lane = tid & 63;
    const int wv   = tid >> 6;
    const int ray  = blockIdx.x * WAVES_PER_BLOCK + wv;
    const int r15  = lane & 15;   // A-row / C-col index
    const int kgrp = lane >> 4;   // k-group (quad)

    // All LDS use is strictly intra-wave (per-wv slices); DS ops execute in
    // program order per wave (proven by barrier-free s_cm path in R3/R4),
    // so NO __syncthreads() anywhere — avoids convoying 4 independent rays.
    __shared__ float s_cm  [WAVES_PER_BLOCK][128]; // granule 4t: {c2t,c2t+1,m2t,m2t+1}
    __shared__ float s_zmid[WAVES_PER_BLOCK][64];
    __shared__ float s_cdf [WAVES_PER_BLOCK][64];
    __shared__ float s_zall[WAVES_PER_BLOCK][128];
    __shared__ float s_out [WAVES_PER_BLOCK][4 * 132]; // [output][fine-sample], stride 132

    // ---- B-fragments for layer-2 MFMA: W2[64 x 16] (cols: sigma,r,g,b,0..)
    // built once per wave; kills all in-loop scalar weight loads.
    // B layout (16x16x32): lane holds B[k = kgrp*8+j + 32q][n = r15]
    half8 bfrag[2];
#pragma unroll
    for (int q = 0; q < 2; ++q) {
#pragma unroll
        for (int j = 0; j < 8; ++j) {
            int k = q * 32 + kgrp * 8 + j;
            float wval = 0.0f;
            if (r15 == 0)      wval = w_sigma[k];
            else if (r15 < 4)  wval = W_rgb[3 * k + (r15 - 1)];
            bfrag[q][j] = (_Float16)wval;
        }
    }

    // ---- ray load + normalize ----
    float ox = rays_o[ray * 3 + 0], oy = rays_o[ray * 3 + 1], oz = rays_o[ray * 3 + 2];
    float dx = rays_d[ray * 3 + 0], dy = rays_d[ray * 3 + 1], dz = rays_d[ray * 3 + 2];
    {
        float inv = __builtin_amdgcn_rsqf(dx * dx + dy * dy + dz * dz);
        dx *= inv; dy *= inv; dz *= inv;
    }

    // ---- near/far vs [-1,1]^3 ----
    float rx = fast_rcp(dx + 1e-15f);
    float ry = fast_rcp(dy + 1e-15f);
    float rz = fast_rcp(dz + 1e-15f);
    float t0x = (-1.0f - ox) * rx, t1x = (1.0f - ox) * rx;
    float t0y = (-1.0f - oy) * ry, t1y = (1.0f - oy) * ry;
    float t0z = (-1.0f - oz) * rz, t1z = (1.0f - oz) * rz;
    float nearv = fmaxf(fmaxf(fminf(t0x, t1x), fminf(t0y, t1y)), fminf(t0z, t1z));
    float farv  = fminf(fminf(fmaxf(t0x, t1x), fmaxf(t0y, t1y)), fmaxf(t0z, t1z));
    const bool miss = (farv < nearv);
    if (miss) { nearv = 1e9f; farv = 1e9f; }
    nearv = fmaxf(nearv, 0.05f);
    const float sample_dist = (farv - nearv) * (1.0f / 64.0f);

    const float bs0 = b_sigma[0];
    const float br0 = b_rgb[0], br1 = b_rgb[1], br2 = b_rgb[2];

    // ---- per-ray affine layer-1: a_j(z) = c_j + m_j*z ----
    {
        float w1x = W1[lane], w1y = W1[64 + lane], w1z = W1[128 + lane];
        float eox = ox, eoy = oy, eoz = oz, msc = 1.0f;
        if (miss) {
            eox = clamp1(fmaf(dx, 1e9f, ox));
            eoy = clamp1(fmaf(dy, 1e9f, oy));
            eoz = clamp1(fmaf(dz, 1e9f, oz));
            msc = 0.0f;
        }
        float cj = fmaf(eox, w1x, fmaf(eoy, w1y, fmaf(eoz, w1z, b1[lane])));
        float mj = msc * fmaf(dx, w1x, fmaf(dy, w1y, dz * w1z));
        int g = (lane >> 1) * 4 + (lane & 1);
        s_cm[wv][g]     = cj;
        s_cm[wv][g + 2] = mj;
    }

    // ---- coarse samples ----
    float z = nearv + (farv - nearv) * ((float)lane * (1.0f / 63.0f));

    // ---- coarse MLP (sigma only), VALU affine form ----
    const v2f* ws2 = (const v2f*)w_sigma;
    v2f z2c = v2_splat(z);
    v2f acc0 = (v2f){bs0, 0.0f};
#pragma unroll 8
    for (int t = 0; t < 32; ++t) {
        v4f g = *(const v4f*)&s_cm[wv][4 * t];
        v2f h = v2_max0(v2_fma((v2f){g.z, g.w}, z2c, (v2f){g.x, g.y}));
        acc0 = v2_fma(h, ws2[t], acc0);
    }
    float sigma = softplus_f(acc0.x + acc0.y);

    // ---- coarse alpha compositing -> weights ----
    float z_next = fdpp<DPP_WF_SL1>(0.0f, z);
    float delta  = (lane < 63) ? (z_next - z) : sample_dist;
    float alpha  = 1.0f - __expf(-delta * sigma);
    float v      = 1.0f - alpha + 1e-15f;
    float incl   = scan_mul_dpp(v);
    float trans  = fdpp<DPP_WF_SR1>(1.0f, incl);
    float w = alpha * trans;

    // ---- sample_pdf ----
    float wgt = (lane >= 1 && lane <= 62) ? (w + 1e-5f) : 0.0f;
    float cumw = scan_add_dpp(wgt);
    float total = lane63_bcast(cumw);
    float cdf_incl = cumw * fast_rcp(total);

    float zmid = 0.5f * (z + z_next);
    s_zmid[wv][lane] = (lane < 63) ? zmid : 0.0f;
    s_cdf [wv][lane] = (lane < 63) ? cdf_incl : 2.0f;

    float u = 0.0078125f + (float)lane * 0.015625f;
    int ind = count_le64(s_cdf[wv], u);
    int below = ind - 1;
    int above = (ind < 62) ? ind : 62;
    float cb = s_cdf[wv][below], ca = s_cdf[wv][above];
    float bb = s_zmid[wv][below], ba = s_zmid[wv][above];
    float denom = ca - cb;
    if (denom < 1e-5f) denom = 1.0f;
    float t = (u - cb) * fast_rcp(denom);
    float nz = fmaf(t, ba - bb, bb);

    // ---- rank-merge concat(z, new_z) -> 128 sorted ----
    s_zmid[wv][lane] = z;
    s_cdf [wv][lane] = nz;
    int pa = lane + count_lt64(s_cdf [wv], z);
    int pb = lane + count_le64(s_zmid[wv], nz);
    s_zall[wv][pa] = z;
    s_zall[wv][pb] = nz;

    float za0 = s_zall[wv][2 * lane + 0];
    float za1 = s_zall[wv][2 * lane + 1];

    // ---- fine MLP via MFMA: per M-tile of 16 samples, D[16s x 16o] ----
    // A layout: lane holds A[m=r15][k=kgrp*8+j (+32q)] = h(sample Mbase+r15, unit k)
    // C/D layout: lane holds D[row=kgrp*4+reg][col=r15]
    {
        float biasv = (r15 == 0) ? bs0 : (r15 == 1) ? br0 : (r15 == 2) ? br1
                     : (r15 == 3) ? br2 : 0.0f;
        v4f accInit = (v4f){biasv, biasv, biasv, biasv};
#pragma unroll 2
        for (int mt = 0; mt < 8; ++mt) {
            const int Mbase = mt * 16;
            float zs = s_zall[wv][Mbase + r15];   // broadcast x4, conflict-free
            v2f zz = v2_splat(zs);
            v4f acc = accInit;
#pragma unroll
            for (int q = 0; q < 2; ++q) {
                half8 afrag;
#pragma unroll
                for (int g4 = 0; g4 < 4; ++g4) {
                    v4f g = *(const v4f*)&s_cm[wv][4 * (q * 16 + kgrp * 4 + g4)];
                    v2f hp = v2_max0(v2_fma((v2f){g.z, g.w}, zz, (v2f){g.x, g.y}));
                    fp16v2 pk = __builtin_amdgcn_cvt_pkrtz(hp.x, hp.y);
                    afrag[2 * g4]     = (_Float16)pk.x;
                    afrag[2 * g4 + 1] = (_Float16)pk.y;
                }
                acc = __builtin_amdgcn_mfma_f32_16x16x32_f16(afrag, bfrag[q], acc, 0, 0, 0);
            }
            if (r15 < 4) {  // cols 0..3 hold sigma,r,g,b for rows kgrp*4+0..3
                *(v4f*)&s_out[wv][r15 * 132 + Mbase + kgrp * 4] = acc;
            }
        }
    }

    // ---- gather per-sample outputs (lane k -> samples 2k, 2k+1) ----
    v2f sgp = *(const v2f*)&s_out[wv][0 * 132 + 2 * lane];
    v2f rp  = *(const v2f*)&s_out[wv][1 * 132 + 2 * lane];
    v2f gp  = *(const v2f*)&s_out[wv][2 * 132 + 2 * lane];
    v2f bp  = *(const v2f*)&s_out[wv][3 * 132 + 2 * lane];

    float sg0 = softplus_f(sgp.x), sg1 = softplus_f(sgp.y);
    float r0 = sigmoid_f(rp.x),   r1 = sigmoid_f(rp.y);
    float g0 = sigmoid_f(gp.x),   g1 = sigmoid_f(gp.y);
    float bl0 = sigmoid_f(bp.x),  bl1 = sigmoid_f(bp.y);

    // ---- fine compositing over 128 samples (2/lane) ----
    float zn0 = fdpp<DPP_WF_SL1>(0.0f, za0);
    float d0 = za1 - za0;
    float d1 = (lane < 63) ? (zn0 - za1) : sample_dist;
    float a0 = 1.0f - __expf(-d0 * sg0);
    float a1 = 1.0f - __expf(-d1 * sg1);
    float v0 = 1.0f - a0 + 1e-15f;
    float v1 = 1.0f - a1 + 1e-15f;
    float local = v0 * v1;
    float incl2 = scan_mul_dpp(local);
    float eprod = fdpp<DPP_WF_SR1>(1.0f, incl2);
    float w0 = a0 * eprod;
    float w1 = a1 * (eprod * v0);

    float wsum = wave_sum_dpp(w0 + w1);
    float rs   = wave_sum_dpp(fmaf(w0, r0,  w1 * r1));
    float gs   = wave_sum_dpp(fmaf(w0, g0,  w1 * g1));
    float bs   = wave_sum_dpp(fmaf(w0, bl0, w1 * bl1));

    if (lane == 0) {
        float bg = 1.0f - wsum;
        out[ray * 3 + 0] = rs + bg;
        out[ray * 3 + 1] = gs + bg;
        out[ray * 3 + 2] = bs + bg;
    }
}

extern "C" void kernel_launch(void* const* d_in, const int* in_sizes, int n_in,
                              void* d_out, int out_size, void* d_ws, size_t ws_size,
                              hipStream_t stream) {
    const float* rays_o  = (const float*)d_in[0];
    const float* rays_d  = (const float*)d_in[1];
    const float* W1      = (const float*)d_in[2];
    const float* b1      = (const float*)d_in[3];
    const float* w_sigma = (const float*)d_in[4];
    const float* b_sigma = (const float*)d_in[5];
    const float* W_rgb   = (const float*)d_in[6];
    const float* b_rgb   = (const float*)d_in[7];
    float* out = (float*)d_out;

    const int n_rays = in_sizes[0] / 3;
    dim3 grid((n_rays + WAVES_PER_BLOCK - 1) / WAVES_PER_BLOCK);
    dim3 block(WAVES_PER_BLOCK * 64);
    hipLaunchKernelGGL(nerf_render_kernel, grid, block, 0, stream,
                       rays_o, rays_d, W1, b1, w_sigma, b_sigma, W_rgb, b_rgb, out);
}

// Round 7
// 98.734 us; speedup vs baseline: 1.0050x; 1.0050x over previous
//
#include <hip/hip_runtime.h>
#include <math.h>

#define WAVES_PER_BLOCK 4

typedef float v2f __attribute__((ext_vector_type(2)));
typedef float v4f __attribute__((ext_vector_type(4)));
typedef __fp16 fp16v2 __attribute__((ext_vector_type(2)));
typedef _Float16 half8 __attribute__((ext_vector_type(8)));

__device__ __forceinline__ v2f v2_fma(v2f a, v2f b, v2f c) {
    return __builtin_elementwise_fma(a, b, c);
}
__device__ __forceinline__ v2f v2_max0(v2f a) {
    return __builtin_elementwise_max(a, (v2f){0.0f, 0.0f});
}
__device__ __forceinline__ v2f v2_splat(float x) { return (v2f){x, x}; }

__device__ __forceinline__ float fast_rcp(float x) { return __builtin_amdgcn_rcpf(x); }

// ---------------- DPP cross-lane primitives ----------------
#define DPP_ROW_SHR(n)  (0x110 | (n))
#define DPP_WF_SL1      0x130
#define DPP_WF_SR1      0x138
#define DPP_ROW_BCAST15 0x142
#define DPP_ROW_BCAST31 0x143

template <int CTRL, int RM = 0xf, int BM = 0xf, bool BC = false>
__device__ __forceinline__ float fdpp(float old_, float src) {
    return __int_as_float(__builtin_amdgcn_update_dpp(
        __float_as_int(old_), __float_as_int(src), CTRL, RM, BM, BC));
}

__device__ __forceinline__ float lane63_bcast(float x) {
    return __int_as_float(__builtin_amdgcn_readlane(__float_as_int(x), 63));
}

__device__ __forceinline__ float scan_add_dpp(float x) {
    x += fdpp<DPP_ROW_SHR(1)>(0.0f, x);
    x += fdpp<DPP_ROW_SHR(2)>(0.0f, x);
    x += fdpp<DPP_ROW_SHR(4)>(0.0f, x);
    x += fdpp<DPP_ROW_SHR(8)>(0.0f, x);
    x += fdpp<DPP_ROW_BCAST15, 0xa>(0.0f, x);
    x += fdpp<DPP_ROW_BCAST31, 0xc>(0.0f, x);
    return x;
}
__device__ __forceinline__ float scan_mul_dpp(float x) {
    x *= fdpp<DPP_ROW_SHR(1)>(1.0f, x);
    x *= fdpp<DPP_ROW_SHR(2)>(1.0f, x);
    x *= fdpp<DPP_ROW_SHR(4)>(1.0f, x);
    x *= fdpp<DPP_ROW_SHR(8)>(1.0f, x);
    x *= fdpp<DPP_ROW_BCAST15, 0xa>(1.0f, x);
    x *= fdpp<DPP_ROW_BCAST31, 0xc>(1.0f, x);
    return x;
}
__device__ __forceinline__ float wave_sum_dpp(float x) {
    return lane63_bcast(scan_add_dpp(x));
}

__device__ __forceinline__ float softplus_f(float x) {
    return fmaxf(x, 0.0f) + __logf(1.0f + __expf(-fabsf(x)));
}
__device__ __forceinline__ float sigmoid_f(float x) {
    return fast_rcp(1.0f + __expf(-x));
}
__device__ __forceinline__ float clamp1(float x) {
    return fminf(fmaxf(x, -1.0f), 1.0f);
}

__device__ __forceinline__ int count_lt64(const float* a, float x) {
    int lo = 0, hi = 64;
    while (lo < hi) { int mid = (lo + hi) >> 1; if (a[mid] < x) lo = mid + 1; else hi = mid; }
    return lo;
}
__device__ __forceinline__ int count_le64(const float* a, float x) {
    int lo = 0, hi = 64;
    while (lo < hi) { int mid = (lo + hi) >> 1; if (a[mid] <= x) lo = mid + 1; else hi = mid; }
    return lo;
}

// Build MFMA A-fragment: h = relu(m*z + c) in f32, cvt to f16 at the boundary.
// cr/mr hold the lane's 16 (c,m) in packed-f32 pairs; q selects the K-half.
__device__ __forceinline__ half8 build_afrag(const v2f* cr, const v2f* mr, v2f zz, int q) {
    union { half8 h; fp16v2 p[4]; } af;
#pragma unroll
    for (int g4 = 0; g4 < 4; ++g4) {
        v2f hp = v2_max0(v2_fma(mr[q * 4 + g4], zz, cr[q * 4 + g4]));
        af.p[g4] = __builtin_amdgcn_cvt_pkrtz(hp.x, hp.y);
    }
    return af.h;
}

__global__ __launch_bounds__(WAVES_PER_BLOCK * 64, 4)
void nerf_render_kernel(const float* __restrict__ rays_o,
                        const float* __restrict__ rays_d,
                        const float* __restrict__ W1,      // [3,64]
                        const float* __restrict__ b1,      // [64]
                        const float* __restrict__ w_sigma, // [64,1]
                        const float* __restrict__ b_sigma, // [1]
                        const float* __restrict__ W_rgb,   // [64,3]
                        const float* __restrict__ b_rgb,   // [3]
                        float* __restrict__ out)           // [N,3]
{
    const int tid  = threadIdx.x;
    const int lane = tid & 63;
    const int wv   = tid >> 6;
    const int ray  = blockIdx.x * WAVES_PER_BLOCK + wv;
    const int r15  = lane & 15;   // A-row / C-col index
    const int kgrp = lane >> 4;   // k-group (quad)

    // All LDS strictly intra-wave (per-wv slices); DS ops are program-ordered
    // per wave (proven R3-R6), so no __syncthreads() anywhere.
    __shared__ float s_cm  [WAVES_PER_BLOCK][128]; // granule 4t: {c2t,c2t+1,m2t,m2t+1}
    __shared__ float s_sig [WAVES_PER_BLOCK][64];  // coarse sigma redistribute
    __shared__ float s_zmid[WAVES_PER_BLOCK][64];
    __shared__ float s_cdf [WAVES_PER_BLOCK][64];
    __shared__ float s_zall[WAVES_PER_BLOCK][128];
    __shared__ float s_out [WAVES_PER_BLOCK][4 * 132]; // [output][fine-sample]

    // ---- B-fragments: W2[64 x 16] (cols: sigma,r,g,b,0..) — once per wave.
    // B layout (16x16x32): lane holds B[k = q*32 + kgrp*8 + j][n = r15]
    half8 bfrag[2];
#pragma unroll
    for (int q = 0; q < 2; ++q) {
#pragma unroll
        for (int j = 0; j < 8; ++j) {
            int k = q * 32 + kgrp * 8 + j;
            float wval = 0.0f;
            if (r15 == 0)      wval = w_sigma[k];
            else if (r15 < 4)  wval = W_rgb[3 * k + (r15 - 1)];
            bfrag[q][j] = (_Float16)wval;
        }
    }

    // ---- ray load + normalize ----
    float ox = rays_o[ray * 3 + 0], oy = rays_o[ray * 3 + 1], oz = rays_o[ray * 3 + 2];
    float dx = rays_d[ray * 3 + 0], dy = rays_d[ray * 3 + 1], dz = rays_d[ray * 3 + 2];
    {
        float inv = __builtin_amdgcn_rsqf(dx * dx + dy * dy + dz * dz);
        dx *= inv; dy *= inv; dz *= inv;
    }

    // ---- near/far vs [-1,1]^3 ----
    float rx = fast_rcp(dx + 1e-15f);
    float ry = fast_rcp(dy + 1e-15f);
    float rz = fast_rcp(dz + 1e-15f);
    float t0x = (-1.0f - ox) * rx, t1x = (1.0f - ox) * rx;
    float t0y = (-1.0f - oy) * ry, t1y = (1.0f - oy) * ry;
    float t0z = (-1.0f - oz) * rz, t1z = (1.0f - oz) * rz;
    float nearv = fmaxf(fmaxf(fminf(t0x, t1x), fminf(t0y, t1y)), fminf(t0z, t1z));
    float farv  = fminf(fminf(fmaxf(t0x, t1x), fmaxf(t0y, t1y)), fmaxf(t0z, t1z));
    const bool miss = (farv < nearv);
    if (miss) { nearv = 1e9f; farv = 1e9f; }
    nearv = fmaxf(nearv, 0.05f);
    const float sample_dist = (farv - nearv) * (1.0f / 64.0f);

    const float bs0 = b_sigma[0];
    const float br0 = b_rgb[0], br1 = b_rgb[1], br2 = b_rgb[2];

    // ---- per-ray affine layer-1: a_j(z) = c_j + m_j*z (lane j computes j) ----
    {
        float w1x = W1[lane], w1y = W1[64 + lane], w1z = W1[128 + lane];
        float eox = ox, eoy = oy, eoz = oz, msc = 1.0f;
        if (miss) {
            eox = clamp1(fmaf(dx, 1e9f, ox));
            eoy = clamp1(fmaf(dy, 1e9f, oy));
            eoz = clamp1(fmaf(dz, 1e9f, oz));
            msc = 0.0f;   // miss: m == 0 exactly (z-clamp below relies on this)
        }
        float cj = fmaf(eox, w1x, fmaf(eoy, w1y, fmaf(eoz, w1z, b1[lane])));
        float mj = msc * fmaf(dx, w1x, fmaf(dy, w1y, dz * w1z));
        int g = (lane >> 1) * 4 + (lane & 1);
        s_cm[wv][g]     = cj;
        s_cm[wv][g + 2] = mj;
    }

    // ---- hoist this lane's 16 (c,m) into registers (8 b128, once) ----
    // A-frag k = q*32 + kgrp*8 + {0..7}  ->  granules t = q*16 + kgrp*4 + {0..3}
    v2f cr[8], mr[8];
#pragma unroll
    for (int q = 0; q < 2; ++q) {
#pragma unroll
        for (int g4 = 0; g4 < 4; ++g4) {
            v4f g = *(const v4f*)&s_cm[wv][4 * (q * 16 + kgrp * 4 + g4)];
            cr[q * 4 + g4] = (v2f){g.x, g.y};
            mr[q * 4 + g4] = (v2f){g.z, g.w};
        }
    }

    // bias for C columns 0..3 (sigma,r,g,b); other cols unused
    const float biasv = (r15 == 0) ? bs0 : (r15 == 1) ? br0 : (r15 == 2) ? br1
                       : (r15 == 3) ? br2 : 0.0f;
    const v4f accInit = (v4f){biasv, biasv, biasv, biasv};

    // ---- coarse pass via MFMA: 4 tiles of 16 samples, sigma = col 0 ----
    const float stepz = (farv - nearv) * (1.0f / 63.0f);
#pragma unroll
    for (int mt = 0; mt < 4; ++mt) {
        float zs = fminf(fmaf(stepz, (float)(mt * 16 + r15), nearv), 6.0e4f);
        v2f zz = v2_splat(zs);
        v4f acc = accInit;
        acc = __builtin_amdgcn_mfma_f32_16x16x32_f16(build_afrag(cr, mr, zz, 0), bfrag[0], acc, 0, 0, 0);
        acc = __builtin_amdgcn_mfma_f32_16x16x32_f16(build_afrag(cr, mr, zz, 1), bfrag[1], acc, 0, 0, 0);
        if (r15 == 0) {   // col 0 lanes hold sigma for rows kgrp*4+0..3
            *(v4f*)&s_sig[wv][mt * 16 + kgrp * 4] = acc;
        }
    }
    float sigma = softplus_f(s_sig[wv][lane]);

    // ---- coarse samples (f32, for compositing/resampling) ----
    float z = nearv + (farv - nearv) * ((float)lane * (1.0f / 63.0f));

    // ---- coarse alpha compositing -> weights ----
    float z_next = fdpp<DPP_WF_SL1>(0.0f, z);
    float delta  = (lane < 63) ? (z_next - z) : sample_dist;
    float alpha  = 1.0f - __expf(-delta * sigma);
    float v      = 1.0f - alpha + 1e-15f;
    float incl   = scan_mul_dpp(v);
    float trans  = fdpp<DPP_WF_SR1>(1.0f, incl);
    float w = alpha * trans;

    // ---- sample_pdf ----
    float wgt = (lane >= 1 && lane <= 62) ? (w + 1e-5f) : 0.0f;
    float cumw = scan_add_dpp(wgt);
    float total = lane63_bcast(cumw);
    float cdf_incl = cumw * fast_rcp(total);

    float zmid = 0.5f * (z + z_next);
    s_zmid[wv][lane] = (lane < 63) ? zmid : 0.0f;
    s_cdf [wv][lane] = (lane < 63) ? cdf_incl : 2.0f;

    float u = 0.0078125f + (float)lane * 0.015625f;
    int ind = count_le64(s_cdf[wv], u);
    int below = ind - 1;
    int above = (ind < 62) ? ind : 62;
    float cb = s_cdf[wv][below], ca = s_cdf[wv][above];
    float bb = s_zmid[wv][below], ba = s_zmid[wv][above];
    float denom = ca - cb;
    if (denom < 1e-5f) denom = 1.0f;
    float t = (u - cb) * fast_rcp(denom);
    float nz = fmaf(t, ba - bb, bb);

    // ---- rank-merge concat(z, new_z) -> 128 sorted ----
    s_zmid[wv][lane] = z;
    s_cdf [wv][lane] = nz;
    int pa = lane + count_lt64(s_cdf [wv], z);
    int pb = lane + count_le64(s_zmid[wv], nz);
    s_zall[wv][pa] = z;
    s_zall[wv][pb] = nz;

    float za0 = s_zall[wv][2 * lane + 0];
    float za1 = s_zall[wv][2 * lane + 1];

    // ---- fine pass via MFMA: 8 tiles of 16 samples, cols 0..3 = outputs ----
#pragma unroll 2
    for (int mt = 0; mt < 8; ++mt) {
        const int Mbase = mt * 16;
        float zs = fminf(s_zall[wv][Mbase + r15], 6.0e4f);
        v2f zz = v2_splat(zs);
        v4f acc = accInit;
        acc = __builtin_amdgcn_mfma_f32_16x16x32_f16(build_afrag(cr, mr, zz, 0), bfrag[0], acc, 0, 0, 0);
        acc = __builtin_amdgcn_mfma_f32_16x16x32_f16(build_afrag(cr, mr, zz, 1), bfrag[1], acc, 0, 0, 0);
        if (r15 < 4) {
            *(v4f*)&s_out[wv][r15 * 132 + Mbase + kgrp * 4] = acc;
        }
    }

    // ---- gather per-sample outputs (lane k -> samples 2k, 2k+1) ----
    v2f sgp = *(const v2f*)&s_out[wv][0 * 132 + 2 * lane];
    v2f rp  = *(const v2f*)&s_out[wv][1 * 132 + 2 * lane];
    v2f gp  = *(const v2f*)&s_out[wv][2 * 132 + 2 * lane];
    v2f bp  = *(const v2f*)&s_out[wv][3 * 132 + 2 * lane];

    float sg0 = softplus_f(sgp.x), sg1 = softplus_f(sgp.y);
    float r0 = sigmoid_f(rp.x),   r1 = sigmoid_f(rp.y);
    float g0 = sigmoid_f(gp.x),   g1 = sigmoid_f(gp.y);
    float bl0 = sigmoid_f(bp.x),  bl1 = sigmoid_f(bp.y);

    // ---- fine compositing over 128 samples (2/lane) ----
    float zn0 = fdpp<DPP_WF_SL1>(0.0f, za0);
    float d0 = za1 - za0;
    float d1 = (lane < 63) ? (zn0 - za1) : sample_dist;
    float a0 = 1.0f - __expf(-d0 * sg0);
    float a1 = 1.0f - __expf(-d1 * sg1);
    float v0 = 1.0f - a0 + 1e-15f;
    float v1 = 1.0f - a1 + 1e-15f;
    float local = v0 * v1;
    float incl2 = scan_mul_dpp(local);
    float eprod = fdpp<DPP_WF_SR1>(1.0f, incl2);
    float w0 = a0 * eprod;
    float w1 = a1 * (eprod * v0);

    float wsum = wave_sum_dpp(w0 + w1);
    float rs   = wave_sum_dpp(fmaf(w0, r0,  w1 * r1));
    float gs   = wave_sum_dpp(fmaf(w0, g0,  w1 * g1));
    float bs   = wave_sum_dpp(fmaf(w0, bl0, w1 * bl1));

    if (lane == 0) {
        float bg = 1.0f - wsum;
        out[ray * 3 + 0] = rs + bg;
        out[ray * 3 + 1] = gs + bg;
        out[ray * 3 + 2] = bs + bg;
    }
}

extern "C" void kernel_launch(void* const* d_in, const int* in_sizes, int n_in,
                              void* d_out, int out_size, void* d_ws, size_t ws_size,
                              hipStream_t stream) {
    const float* rays_o  = (const float*)d_in[0];
    const float* rays_d  = (const float*)d_in[1];
    const float* W1      = (const float*)d_in[2];
    const float* b1      = (const float*)d_in[3];
    const float* w_sigma = (const float*)d_in[4];
    const float* b_sigma = (const float*)d_in[5];
    const float* W_rgb   = (const float*)d_in[6];
    const float* b_rgb   = (const float*)d_in[7];
    float* out = (float*)d_out;

    const int n_rays = in_sizes[0] / 3;
    dim3 grid((n_rays + WAVES_PER_BLOCK - 1) / WAVES_PER_BLOCK);
    dim3 block(WAVES_PER_BLOCK * 64);
    hipLaunchKernelGGL(nerf_render_kernel, grid, block, 0, stream,
                       rays_o, rays_d, W1, b1, w_sigma, b_sigma, W_rgb, b_rgb, out);
}

// Round 8
// 98.006 us; speedup vs baseline: 1.0125x; 1.0074x over previous
//
#include <hip/hip_runtime.h>
#include <math.h>

#define WAVES_PER_BLOCK 4

typedef float v2f __attribute__((ext_vector_type(2)));
typedef float v4f __attribute__((ext_vector_type(4)));
typedef __fp16 fp16v2 __attribute__((ext_vector_type(2)));
typedef _Float16 half8 __attribute__((ext_vector_type(8)));

__device__ __forceinline__ v2f v2_fma(v2f a, v2f b, v2f c) {
    return __builtin_elementwise_fma(a, b, c);
}
__device__ __forceinline__ v2f v2_max0(v2f a) {
    return __builtin_elementwise_max(a, (v2f){0.0f, 0.0f});
}
__device__ __forceinline__ v2f v2_splat(float x) { return (v2f){x, x}; }

__device__ __forceinline__ float fast_rcp(float x) { return __builtin_amdgcn_rcpf(x); }

// ---------------- DPP cross-lane primitives ----------------
#define DPP_ROW_SHR(n)  (0x110 | (n))
#define DPP_WF_SL1      0x130
#define DPP_WF_SR1      0x138
#define DPP_ROW_BCAST15 0x142
#define DPP_ROW_BCAST31 0x143

template <int CTRL, int RM = 0xf, int BM = 0xf, bool BC = false>
__device__ __forceinline__ float fdpp(float old_, float src) {
    return __int_as_float(__builtin_amdgcn_update_dpp(
        __float_as_int(old_), __float_as_int(src), CTRL, RM, BM, BC));
}
template <int CTRL, int RM = 0xf, int BM = 0xf, bool BC = false>
__device__ __forceinline__ int idpp(int old_, int src) {
    return __builtin_amdgcn_update_dpp(old_, src, CTRL, RM, BM, BC);
}

__device__ __forceinline__ float lane63_bcast(float x) {
    return __int_as_float(__builtin_amdgcn_readlane(__float_as_int(x), 63));
}

__device__ __forceinline__ float scan_add_dpp(float x) {
    x += fdpp<DPP_ROW_SHR(1)>(0.0f, x);
    x += fdpp<DPP_ROW_SHR(2)>(0.0f, x);
    x += fdpp<DPP_ROW_SHR(4)>(0.0f, x);
    x += fdpp<DPP_ROW_SHR(8)>(0.0f, x);
    x += fdpp<DPP_ROW_BCAST15, 0xa>(0.0f, x);
    x += fdpp<DPP_ROW_BCAST31, 0xc>(0.0f, x);
    return x;
}
__device__ __forceinline__ float scan_mul_dpp(float x) {
    x *= fdpp<DPP_ROW_SHR(1)>(1.0f, x);
    x *= fdpp<DPP_ROW_SHR(2)>(1.0f, x);
    x *= fdpp<DPP_ROW_SHR(4)>(1.0f, x);
    x *= fdpp<DPP_ROW_SHR(8)>(1.0f, x);
    x *= fdpp<DPP_ROW_BCAST15, 0xa>(1.0f, x);
    x *= fdpp<DPP_ROW_BCAST31, 0xc>(1.0f, x);
    return x;
}
__device__ __forceinline__ float wave_sum_dpp(float x) {
    return lane63_bcast(scan_add_dpp(x));
}
__device__ __forceinline__ int imax2(int a, int b) { return a > b ? a : b; }
// inclusive max-scan (int), identity INT_MIN
__device__ __forceinline__ int imax_scan_dpp(int x) {
    const int NEG = (int)0x80000000;
    x = imax2(x, idpp<DPP_ROW_SHR(1)>(NEG, x));
    x = imax2(x, idpp<DPP_ROW_SHR(2)>(NEG, x));
    x = imax2(x, idpp<DPP_ROW_SHR(4)>(NEG, x));
    x = imax2(x, idpp<DPP_ROW_SHR(8)>(NEG, x));
    x = imax2(x, idpp<DPP_ROW_BCAST15, 0xa>(NEG, x));
    x = imax2(x, idpp<DPP_ROW_BCAST31, 0xc>(NEG, x));
    return x;
}

__device__ __forceinline__ float softplus_f(float x) {
    return fmaxf(x, 0.0f) + __logf(1.0f + __expf(-fabsf(x)));
}
__device__ __forceinline__ float sigmoid_f(float x) {
    return fast_rcp(1.0f + __expf(-x));
}
__device__ __forceinline__ float clamp1(float x) {
    return fminf(fmaxf(x, -1.0f), 1.0f);
}

// one bitonic-merge stage at distance d on the 2-regs/lane layout
__device__ __forceinline__ void bstage(float& a, float& b, int d, int lane) {
    float av = __shfl_xor(a, d, 64);
    float bv = __shfl_xor(b, d, 64);
    bool up = (lane & d) != 0;
    float alo = fminf(a, av), ahi = fmaxf(a, av);
    float blo = fminf(b, bv), bhi = fmaxf(b, bv);
    a = up ? ahi : alo;
    b = up ? bhi : blo;
}

// A-fragment: h = relu(m*z + c) in f32, cvt to f16 at the MFMA boundary
__device__ __forceinline__ half8 build_afrag(const v2f* cr, const v2f* mr, v2f zz, int q) {
    union { half8 h; fp16v2 p[4]; } af;
#pragma unroll
    for (int g4 = 0; g4 < 4; ++g4) {
        v2f hp = v2_max0(v2_fma(mr[q * 4 + g4], zz, cr[q * 4 + g4]));
        af.p[g4] = __builtin_amdgcn_cvt_pkrtz(hp.x, hp.y);
    }
    return af.h;
}

__global__ __launch_bounds__(WAVES_PER_BLOCK * 64, 4)
void nerf_render_kernel(const float* __restrict__ rays_o,
                        const float* __restrict__ rays_d,
                        const float* __restrict__ W1,      // [3,64]
                        const float* __restrict__ b1,      // [64]
                        const float* __restrict__ w_sigma, // [64,1]
                        const float* __restrict__ b_sigma, // [1]
                        const float* __restrict__ W_rgb,   // [64,3]
                        const float* __restrict__ b_rgb,   // [3]
                        float* __restrict__ out)           // [N,3]
{
    const int tid  = threadIdx.x;
    const int lane = tid & 63;
    const int wv   = tid >> 6;
    const int ray  = blockIdx.x * WAVES_PER_BLOCK + wv;
    const int r15  = lane & 15;
    const int kgrp = lane >> 4;

    // All LDS strictly intra-wave; DS ops program-ordered per wave (R3-R7).
    __shared__ float s_cm [WAVES_PER_BLOCK][128]; // granule 4t: {c2t,c2t+1,m2t,m2t+1}
    __shared__ int   s_scr[WAVES_PER_BLOCK][64];  // cdf-rank scatter table
    __shared__ float s_sig[WAVES_PER_BLOCK][64];  // coarse sigma redistribute
    __shared__ float s_out[WAVES_PER_BLOCK][4 * 132];

    // ---- B-fragments: W2[64 x 16] (cols sigma,r,g,b,0..) once per wave ----
    half8 bfrag[2];
#pragma unroll
    for (int q = 0; q < 2; ++q) {
#pragma unroll
        for (int j = 0; j < 8; ++j) {
            int k = q * 32 + kgrp * 8 + j;
            float wval = 0.0f;
            if (r15 == 0)      wval = w_sigma[k];
            else if (r15 < 4)  wval = W_rgb[3 * k + (r15 - 1)];
            bfrag[q][j] = (_Float16)wval;
        }
    }

    // ---- ray load + normalize ----
    float ox = rays_o[ray * 3 + 0], oy = rays_o[ray * 3 + 1], oz = rays_o[ray * 3 + 2];
    float dx = rays_d[ray * 3 + 0], dy = rays_d[ray * 3 + 1], dz = rays_d[ray * 3 + 2];
    {
        float inv = __builtin_amdgcn_rsqf(dx * dx + dy * dy + dz * dz);
        dx *= inv; dy *= inv; dz *= inv;
    }

    // ---- near/far vs [-1,1]^3 ----
    float rx = fast_rcp(dx + 1e-15f);
    float ry = fast_rcp(dy + 1e-15f);
    float rz = fast_rcp(dz + 1e-15f);
    float t0x = (-1.0f - ox) * rx, t1x = (1.0f - ox) * rx;
    float t0y = (-1.0f - oy) * ry, t1y = (1.0f - oy) * ry;
    float t0z = (-1.0f - oz) * rz, t1z = (1.0f - oz) * rz;
    float nearv = fmaxf(fmaxf(fminf(t0x, t1x), fminf(t0y, t1y)), fminf(t0z, t1z));
    float farv  = fminf(fminf(fmaxf(t0x, t1x), fmaxf(t0y, t1y)), fmaxf(t0z, t1z));
    const bool miss = (farv < nearv);
    if (miss) { nearv = 1e9f; farv = 1e9f; }
    nearv = fmaxf(nearv, 0.05f);
    const float sample_dist = (farv - nearv) * (1.0f / 64.0f);

    const float bs0 = b_sigma[0];
    const float br0 = b_rgb[0], br1 = b_rgb[1], br2 = b_rgb[2];

    // ---- per-ray affine layer-1: a_j(z) = c_j + m_j*z ----
    {
        float w1x = W1[lane], w1y = W1[64 + lane], w1z = W1[128 + lane];
        float eox = ox, eoy = oy, eoz = oz, msc = 1.0f;
        if (miss) {
            eox = clamp1(fmaf(dx, 1e9f, ox));
            eoy = clamp1(fmaf(dy, 1e9f, oy));
            eoz = clamp1(fmaf(dz, 1e9f, oz));
            msc = 0.0f;
        }
        float cj = fmaf(eox, w1x, fmaf(eoy, w1y, fmaf(eoz, w1z, b1[lane])));
        float mj = msc * fmaf(dx, w1x, fmaf(dy, w1y, dz * w1z));
        int g = (lane >> 1) * 4 + (lane & 1);
        s_cm[wv][g]     = cj;
        s_cm[wv][g + 2] = mj;
    }

    // ---- hoist this lane's 16 (c,m) into registers (8 b128, once) ----
    v2f cr[8], mr[8];
#pragma unroll
    for (int q = 0; q < 2; ++q) {
#pragma unroll
        for (int g4 = 0; g4 < 4; ++g4) {
            v4f g = *(const v4f*)&s_cm[wv][4 * (q * 16 + kgrp * 4 + g4)];
            cr[q * 4 + g4] = (v2f){g.x, g.y};
            mr[q * 4 + g4] = (v2f){g.z, g.w};
        }
    }

    const float biasv = (r15 == 0) ? bs0 : (r15 == 1) ? br0 : (r15 == 2) ? br1
                       : (r15 == 3) ? br2 : 0.0f;
    const v4f accInit = (v4f){biasv, biasv, biasv, biasv};

    // ---- coarse pass via MFMA (sigma = col 0) ----
    const float stepz = (farv - nearv) * (1.0f / 63.0f);
#pragma unroll
    for (int mt = 0; mt < 4; ++mt) {
        float zs = fminf(fmaf(stepz, (float)(mt * 16 + r15), nearv), 6.0e4f);
        v2f zz = v2_splat(zs);
        v4f acc = accInit;
        acc = __builtin_amdgcn_mfma_f32_16x16x32_f16(build_afrag(cr, mr, zz, 0), bfrag[0], acc, 0, 0, 0);
        acc = __builtin_amdgcn_mfma_f32_16x16x32_f16(build_afrag(cr, mr, zz, 1), bfrag[1], acc, 0, 0, 0);
        if (r15 == 0) {
            *(v4f*)&s_sig[wv][mt * 16 + kgrp * 4] = acc;
        }
    }
    float sigma = softplus_f(s_sig[wv][lane]);

    // ---- coarse samples ----
    float z = nearv + (farv - nearv) * ((float)lane * (1.0f / 63.0f));

    // ---- coarse alpha compositing -> weights ----
    float z_next = fdpp<DPP_WF_SL1>(0.0f, z);
    float delta  = (lane < 63) ? (z_next - z) : sample_dist;
    float alpha  = 1.0f - __expf(-delta * sigma);
    float v      = 1.0f - alpha + 1e-15f;
    float incl   = scan_mul_dpp(v);
    float trans  = fdpp<DPP_WF_SR1>(1.0f, incl);
    float w = alpha * trans;

    // ---- sample_pdf: cdf scan then CLOSED-FORM inverse vs the uniform u-grid.
    // u_i=(2i+1)/128; cdf_k <= u_i  <=>  s_k := clamp(ceil(64*cdf_k-0.5),0,64) <= i.
    // below_i = max{k: s_k <= i} via group-last scatter + int max-scan (no search).
    float wgt = (lane >= 1 && lane <= 62) ? (w + 1e-5f) : 0.0f;
    float cumw = scan_add_dpp(wgt);
    float total = lane63_bcast(cumw);
    float cdf_incl = cumw * fast_rcp(total);

    float cdfv  = (lane < 63) ? cdf_incl : 2.0f;           // lane63 sentinel
    float zmidv = (lane < 63) ? (0.5f * (z + z_next)) : 0.0f;

    int s = (int)ceilf(fmaf(64.0f, cdfv, -0.5f));
    s = s < 0 ? 0 : (s > 64 ? 64 : s);
    int snext = idpp<DPP_WF_SL1>(65, s);
    bool glast = (snext > s) && (s < 64);

    s_scr[wv][lane] = -1;
    if (glast) s_scr[wv][s] = lane;    // distinct slots among active lanes
    int below = imax_scan_dpp(s_scr[wv][lane]);   // >=0 (s_0 == 0 always)
    int above = below + 1; if (above > 62) above = 62;

    float cb = __shfl(cdfv,  below, 64);
    float ca = __shfl(cdfv,  above, 64);
    float bb = __shfl(zmidv, below, 64);
    float ba = __shfl(zmidv, above, 64);
    float denom = ca - cb;
    if (denom < 1e-5f) denom = 1.0f;
    float t = (__shfl(cdfv, 0, 64) * 0.0f + (0.0078125f + (float)lane * 0.015625f) - cb) * fast_rcp(denom);
    float nz = fmaf(t, ba - bb, bb);   // ascending in lane

    // ---- in-register bitonic merge of z (asc) and nz (asc) -> 128 sorted ----
    float r0v = z;
    float r1v = __shfl(nz, 63 - lane, 64);   // reversed -> bitonic concat
    {   // stage d=64 (in-lane)
        float lo = fminf(r0v, r1v), hi = fmaxf(r0v, r1v);
        r0v = lo; r1v = hi;
    }
    bstage(r0v, r1v, 32, lane);
    bstage(r0v, r1v, 16, lane);
    bstage(r0v, r1v,  8, lane);
    bstage(r0v, r1v,  4, lane);
    bstage(r0v, r1v,  2, lane);
    bstage(r0v, r1v,  1, lane);
    // z_all[i] = (i<64) ? r0v@lane=i : r1v@lane=i-64

    // ---- fine pass via MFMA: 8 tiles of 16 samples ----
#pragma unroll 2
    for (int mt = 0; mt < 8; ++mt) {
        const int Mbase = mt * 16;
        float zraw = (mt < 4) ? __shfl(r0v, Mbase + r15, 64)
                              : __shfl(r1v, (Mbase - 64) + r15, 64);
        float zs = fminf(zraw, 6.0e4f);
        v2f zz = v2_splat(zs);
        v4f acc = accInit;
        acc = __builtin_amdgcn_mfma_f32_16x16x32_f16(build_afrag(cr, mr, zz, 0), bfrag[0], acc, 0, 0, 0);
        acc = __builtin_amdgcn_mfma_f32_16x16x32_f16(build_afrag(cr, mr, zz, 1), bfrag[1], acc, 0, 0, 0);
        if (r15 < 4) {
            *(v4f*)&s_out[wv][r15 * 132 + Mbase + kgrp * 4] = acc;
        }
    }

    // ---- gather per-sample z pairs from merge registers ----
    int i0 = 2 * lane, i1 = 2 * lane + 1;
    float a0r = __shfl(r0v, i0 & 63, 64), a0s = __shfl(r1v, i0 & 63, 64);
    float a1r = __shfl(r0v, i1 & 63, 64), a1s = __shfl(r1v, i1 & 63, 64);
    float za0 = (i0 < 64) ? a0r : a0s;
    float za1 = (i1 < 64) ? a1r : a1s;

    // ---- per-sample outputs ----
    v2f sgp = *(const v2f*)&s_out[wv][0 * 132 + 2 * lane];
    v2f rp  = *(const v2f*)&s_out[wv][1 * 132 + 2 * lane];
    v2f gp  = *(const v2f*)&s_out[wv][2 * 132 + 2 * lane];
    v2f bp  = *(const v2f*)&s_out[wv][3 * 132 + 2 * lane];

    float sg0 = softplus_f(sgp.x), sg1 = softplus_f(sgp.y);
    float r0c = sigmoid_f(rp.x),   r1c = sigmoid_f(rp.y);
    float g0c = sigmoid_f(gp.x),   g1c = sigmoid_f(gp.y);
    float b0c = sigmoid_f(bp.x),   b1c = sigmoid_f(bp.y);

    // ---- fine compositing over 128 samples (2/lane) ----
    float zn0 = fdpp<DPP_WF_SL1>(0.0f, za0);
    float d0 = za1 - za0;
    float d1 = (lane < 63) ? (zn0 - za1) : sample_dist;
    float aa0 = 1.0f - __expf(-d0 * sg0);
    float aa1 = 1.0f - __expf(-d1 * sg1);
    float v0 = 1.0f - aa0 + 1e-15f;
    float v1 = 1.0f - aa1 + 1e-15f;
    float local = v0 * v1;
    float incl2 = scan_mul_dpp(local);
    float eprod = fdpp<DPP_WF_SR1>(1.0f, incl2);
    float w0 = aa0 * eprod;
    float w1 = aa1 * (eprod * v0);

    float wsum = wave_sum_dpp(w0 + w1);
    float rs   = wave_sum_dpp(fmaf(w0, r0c, w1 * r1c));
    float gs   = wave_sum_dpp(fmaf(w0, g0c, w1 * g1c));
    float bs   = wave_sum_dpp(fmaf(w0, b0c, w1 * b1c));

    if (lane == 0) {
        float bg = 1.0f - wsum;
        out[ray * 3 + 0] = rs + bg;
        out[ray * 3 + 1] = gs + bg;
        out[ray * 3 + 2] = bs + bg;
    }
}

extern "C" void kernel_launch(void* const* d_in, const int* in_sizes, int n_in,
                              void* d_out, int out_size, void* d_ws, size_t ws_size,
                              hipStream_t stream) {
    const float* rays_o  = (const float*)d_in[0];
    const float* rays_d  = (const float*)d_in[1];
    const float* W1      = (const float*)d_in[2];
    const float* b1      = (const float*)d_in[3];
    const float* w_sigma = (const float*)d_in[4];
    const float* b_sigma = (const float*)d_in[5];
    const float* W_rgb   = (const float*)d_in[6];
    const float* b_rgb   = (const float*)d_in[7];
    float* out = (float*)d_out;

    const int n_rays = in_sizes[0] / 3;
    dim3 grid((n_rays + WAVES_PER_BLOCK - 1) / WAVES_PER_BLOCK);
    dim3 block(WAVES_PER_BLOCK * 64);
    hipLaunchKernelGGL(nerf_render_kernel, grid, block, 0, stream,
                       rays_o, rays_d, W1, b1, w_sigma, b_sigma, W_rgb, b_rgb, out);
}